// Round 16
// baseline (2245.510 us; speedup 1.0000x reference)
//
#include <hip/hip_runtime.h>
#include <hip/hip_bf16.h>
#include <cstddef>
#include <cstdint>

#define LEAK  0.99f
#define THRS  1.0f
#define BNEPS 1e-4f

static constexpr int TT   = 8;
static constexpr int BB   = 4;
static constexpr int NCLS = 21;

typedef __attribute__((ext_vector_type(8))) short short8v;   // 8 bf16 (MFMA A/B frag)
typedef __attribute__((ext_vector_type(4))) float f32x4;     // 16x16 C/D frag
typedef __attribute__((ext_vector_type(16))) float f32x16;   // 32x32 C/D frag

__global__ void zero_f32(float* __restrict__ p, int n) {
  int i = blockIdx.x * blockDim.x + threadIdx.x;
  int stride = gridDim.x * blockDim.x;
  for (; i < n; i += stride) p[i] = 0.0f;
}

__global__ void scale_f32(float* __restrict__ p, int n, float s) {
  int i = blockIdx.x * blockDim.x + threadIdx.x;
  if (i < n) p[i] *= s;
}

// Split f32 weights (scaled) into hi+lo bf16, reordered to k = tap*Cip + ci.
__global__ void wsplit(const float* __restrict__ Wsrc,
                       __hip_bfloat16* __restrict__ whi, __hip_bfloat16* __restrict__ wlo,
                       int Co, int Ci, int Cip, float scale) {
  const int Kpad = 9 * Cip;
  const int n = Co * Kpad;
  int i = blockIdx.x * 256 + threadIdx.x;
  if (i >= n) return;
  int co = i / Kpad, k = i - co * Kpad;
  int tap = k / Cip, ci = k - tap * Cip;
  float w = 0.0f;
  if (ci < Ci) w = Wsrc[((size_t)co * Ci + ci) * 9 + tap] * scale;
  __hip_bfloat16 h = __float2bfloat16(w);
  float r = w - __bfloat162float(h);
  whi[i] = h;
  wlo[i] = __float2bfloat16(r);
}

// L0 packed weights: k = slot*8 + ci, 12 slots (9 taps + 3 zero), 8ch (3 real).
__global__ void wsplit_l0(const float* __restrict__ W0,
                          __hip_bfloat16* __restrict__ whi, __hip_bfloat16* __restrict__ wlo) {
  int i = blockIdx.x * 256 + threadIdx.x;      // co*96 + k
  if (i >= 64 * 96) return;
  int co = i / 96, k = i - co * 96;
  int slot = k >> 3, ci = k & 7;
  float w = 0.0f;
  if (slot < 9 && ci < 3) w = W0[((size_t)co * 3 + ci) * 9 + slot];
  __hip_bfloat16 h = __float2bfloat16(w);
  float r = w - __bfloat162float(h);
  whi[i] = h;
  wlo[i] = __float2bfloat16(r);
}

// Poisson generator -> channel-last [B*HW][8] (ch 3..7 zero), one 16B store/px.
__global__ void spike_gen8(const float* __restrict__ x, const float* __restrict__ u,
                           __hip_bfloat16* __restrict__ spk) {
  const int HW = 128 * 128;
  int i = blockIdx.x * 256 + threadIdx.x;  // b*HW + hw
  if (i >= BB * HW) return;
  int b = i / HW, hw = i - b * HW;
  short8v o = {};
#pragma unroll
  for (int c = 0; c < 3; ++c) {
    float xv = x[((size_t)b * 3 + c) * HW + hw];
    float uv = u[((size_t)b * 3 + c) * HW + hw];
    float ax = fabsf(xv);
    float sg = (xv > 0.0f) ? 1.0f : ((xv < 0.0f) ? -1.0f : 0.0f);
    float s  = (uv <= ax) ? sg : 0.0f;
    __hip_bfloat16_raw raw = __hip_bfloat16_raw(__float2bfloat16(s));
    o[c] = (short)raw.x;
  }
  *(short8v*)(spk + (size_t)i * 8) = o;
}

// L0 dedicated (r13): tap-packed implicit GEMM, K = 96 (12 slots x 8ch), 3 chunks.
__global__ __launch_bounds__(256) void gemm_lif_l0(
    const __hip_bfloat16* __restrict__ spk,   // [B*HW][8]
    const __hip_bfloat16* __restrict__ wsp,   // [2][64][96] hi, lo
    const float* __restrict__ bnt, float* __restrict__ mem,
    __hip_bfloat16* __restrict__ actout,
    const __hip_bfloat16* __restrict__ zp) {
  constexpr int M = 2, Co = 64, Kpk = 96, HW = 16384, H = 128, W = 128;
  __shared__ __hip_bfloat16 lds[3 * 64 * 32];
  const int lane = threadIdx.x & 63, wid = threadIdx.x >> 6;
  const int l15 = lane & 15, g = lane >> 4;

  const int nb = gridDim.x;
  const int flat = blockIdx.x;
  const int swz = (flat & 7) * (nb >> 3) + (flat >> 3);
  const int bx = swz & 511, by = swz >> 9;
  const int p0 = (bx * 4 + wid) * 32;
  const int co0 = by * 32;

  int b_[M], y_[M], x_[M];
#pragma unroll
  for (int m = 0; m < M; ++m) {
    int pb = p0 + m * 16;
    b_[m] = pb >> 14;
    int rem = pb & (HW - 1);
    y_[m] = rem >> 7;
    x_[m] = (rem & 127) + l15;
  }

  unsigned sgb[3];
#pragma unroll
  for (int i = 0; i < 3; ++i) {
    int f = wid * 48 + i * 16 + (lane >> 2);
    int cc = f >> 6;
    int r  = f & 63;
    int half = r >> 5;
    int co   = r & 31;
    int slot = (lane & 3) ^ ((co >> 1) & 3);
    sgb[i] = (unsigned)half * Co * Kpk + (unsigned)(co0 + co) * Kpk + slot * 8 + cc * 32;
  }
#pragma unroll
  for (int i = 0; i < 3; ++i) {
    const __hip_bfloat16* gp = wsp + sgb[i];
    __hip_bfloat16* lp = &lds[(wid * 48 + i * 16) * 32];
    __builtin_amdgcn_global_load_lds(
        (const __attribute__((address_space(1))) void*)gp,
        (__attribute__((address_space(3))) void*)lp, 16, 0, 0);
  }

  short8v aA[3][M];
#pragma unroll
  for (int c = 0; c < 3; ++c) {
    int tap = c * 4 + g;
    int ty = (tap * 11) >> 5;
    int tx = tap - ty * 3;
    int dy = ty - 1, dx = tx - 1;
#pragma unroll
    for (int m = 0; m < M; ++m) {
      int sy = y_[m] + dy, sx = x_[m] + dx;
      bool v = (tap < 9) & (sy >= 0) & (sy < H) & (sx >= 0) & (sx < W);
      int pix = (b_[m] << 14) + (sy << 7) + sx;
      const __hip_bfloat16* ap = v ? (spk + (size_t)pix * 8) : zp;
      aA[c][m] = *(const short8v*)ap;
    }
  }

  asm volatile("s_waitcnt vmcnt(%0)" :: "n"(6) : "memory");
  __builtin_amdgcn_s_barrier();
  __builtin_amdgcn_sched_barrier(0);

  f32x4 acc[M][2] = {};
  const int rdb = l15 * 32 + ((g ^ ((l15 >> 1) & 3)) * 8);
#pragma unroll
  for (int c = 0; c < 3; ++c) {
    short8v bh[2], bl[2];
#pragma unroll
    for (int j = 0; j < 2; ++j) {
      bh[j] = *(const short8v*)(&lds[c * 2048] + j * 512 + rdb);
      bl[j] = *(const short8v*)(&lds[c * 2048] + 1024 + j * 512 + rdb);
    }
    __builtin_amdgcn_s_setprio(1);
#pragma unroll
    for (int j = 0; j < 2; ++j)
#pragma unroll
      for (int m = 0; m < M; ++m) {
        acc[m][j] = __builtin_amdgcn_mfma_f32_16x16x32_bf16(aA[c][m], bh[j], acc[m][j], 0, 0, 0);
        acc[m][j] = __builtin_amdgcn_mfma_f32_16x16x32_bf16(aA[c][m], bl[j], acc[m][j], 0, 0, 0);
      }
    __builtin_amdgcn_s_setprio(0);
  }

#pragma unroll
  for (int j = 0; j < 2; ++j) {
    int c = co0 + j * 16 + l15;
    float ga = bnt[c], mu = bnt[Co + c], va = bnt[2 * Co + c];
    float sc = ga / sqrtf(va + BNEPS);
#pragma unroll
    for (int m = 0; m < M; ++m) {
      int pixb = p0 + m * 16 + 4 * g;
#pragma unroll
      for (int r = 0; r < 4; ++r) {
        size_t idx = (size_t)(pixb + r) * Co + c;
        float bno = (acc[m][j][r] - mu) * sc;
        float mv = LEAK * mem[idx] + bno;
        float s = (mv > THRS) ? 1.0f : 0.0f;
        actout[idx] = __float2bfloat16(s);
        mem[idx] = mv - s;
      }
    }
  }
}

// Generic implicit-GEMM conv3x3(pad==dil) + BN + LIF (r12/r13 pipeline).
// M==1: 16x16x32 MFMA path (r13 verbatim; row-major LDS + slot swizzle).
// M==2: 32x32x16 MFMA path with K-MAJOR LDS layout [chunk][half][slot(4)][co(16N)]
//       -> B-reads are contiguous 512B per 32-lane half: zero bank conflicts,
//       no swizzle needed. Staging stays linear-dest; global source permuted.
template<int M, int N, int GRP, int CPT, int SPLIT>
__global__ __launch_bounds__(SPLIT * 256, 4) void gemm_lif(
    const __hip_bfloat16* __restrict__ actin,
    const __hip_bfloat16* __restrict__ wsp,      // [2][Co][Kpad] hi, lo
    const float* __restrict__ bnt,               // [3][Co] for this timestep
    float* __restrict__ mem, __hip_bfloat16* __restrict__ actout,
    const __hip_bfloat16* __restrict__ zp,
    int Co, int lgHW, int lgW, int dil, int lgGX) {
  constexpr int NW = 4;
  constexpr int Cip = CPT * 32;
  constexpr int Kpad = 9 * Cip;
  constexpr int lgcpt = (CPT == 1) ? 0 : (CPT == 2) ? 1 : (CPT == 4) ? 2 : 3;
  constexpr int R  = N * 32;                 // rows (64B) per chunk (hi+lo)
  constexpr int lgR = (N == 1) ? 5 : ((N == 2) ? 6 : 7);
  constexpr int CoB = 16 * N;                // co per block
  constexpr int BUFROWS = GRP * R;
  constexpr int BUFELEM = BUFROWS * 32;
  constexpr int INSTS = BUFROWS / (16 * NW);
  constexpr int AM = M * GRP;
  constexpr int WAITN = AM;
  constexpr int NCH = (9 * CPT) / SPLIT;
  constexpr int NGRP = NCH / GRP;
  static_assert(NCH % GRP == 0, "group must divide per-half chunk count");
  __shared__ __hip_bfloat16 lds[SPLIT * 2 * BUFELEM];

  const int HW = 1 << lgHW, H = HW >> lgW, W = 1 << lgW;
  const unsigned CoKpad = (unsigned)Co * Kpad;
  const int lane = threadIdx.x & 63, wid = threadIdx.x >> 6;
  const int kw = wid >> 2;
  const int wq = wid & 3;
  __hip_bfloat16* ldsh = lds + kw * 2 * BUFELEM;

  const int nb = gridDim.x;
  const int flat = blockIdx.x;
  const int swz = (flat & 7) * (nb >> 3) + (flat >> 3);
  const int bx = swz & ((1 << lgGX) - 1);
  const int by = swz >> lgGX;
  const int p0  = (bx * NW + wq) * (M * 16);
  const int co0 = by * (N * 16);

  const unsigned kbase = (unsigned)kw * (NCH * 32);
  unsigned sgb[INSTS];
  if constexpr (M == 1) {
    // row-major layout [chunk][half][co][slot], slot XOR-swizzled on global src
#pragma unroll
    for (int i = 0; i < INSTS; ++i) {
      int f  = wq * (BUFROWS / NW) + i * 16 + (lane >> 2);
      int cc = f >> lgR;
      int r  = f & (R - 1);
      int half = r >> (lgR - 1);
      int co   = r & (16 * N - 1);
      int slot = (lane & 3) ^ ((co >> 1) & 3);
      sgb[i] = (unsigned)half * CoKpad + (unsigned)(co0 + co) * Kpad + slot * 8
             + cc * 32 + kbase;
    }
  } else {
    // k-major layout [chunk][half][slot(4)][co(CoB)] in 16B units, NO swizzle
#pragma unroll
    for (int i = 0; i < INSTS; ++i) {
      int u  = wq * (INSTS * 64) + i * 64 + lane;   // 16B unit within buffer
      int cc = u / (R * 4);                          // units per chunk = R*4
      int uc = u - cc * (R * 4);
      int hf = uc / (4 * CoB);
      int rm = uc - hf * (4 * CoB);
      int sl = rm / CoB;
      int co = rm - sl * CoB;
      sgb[i] = (unsigned)hf * CoKpad + (unsigned)(co0 + co) * Kpad + sl * 8
             + cc * 32 + kbase;
    }
  }

  auto stage = [&](int gl, int buf) {
#pragma unroll
    for (int i = 0; i < INSTS; ++i) {
      const __hip_bfloat16* gp = wsp + sgb[i] + gl * (GRP * 32);
      __hip_bfloat16* lp = &ldsh[buf * BUFELEM + (wq * (BUFROWS / NW) + i * 16) * 32];
      __builtin_amdgcn_global_load_lds(
          (const __attribute__((address_space(1))) void*)gp,
          (__attribute__((address_space(3))) void*)lp, 16, 0, 0);
    }
  };

  if constexpr (M == 1) {
    // ================= 16x16x32 path (r13 verbatim, M==1) =================
    const int l15 = lane & 15, g = lane >> 4;

    int b_[M], y_[M], x_[M];
#pragma unroll
    for (int m = 0; m < M; ++m) {
      int pb = p0 + m * 16;
      b_[m] = pb >> lgHW;
      int rem = pb & (HW - 1);
      y_[m] = rem >> lgW;
      x_[m] = (rem & (W - 1)) + l15;
    }

    const __hip_bfloat16* apc[M];
    auto mkaddr = [&](int tap) {
      int ty = (tap * 11) >> 5;
      int tx = tap - ty * 3;
      int dy = (ty - 1) * dil, dx = (tx - 1) * dil;
#pragma unroll
      for (int m = 0; m < M; ++m) {
        int sy = y_[m] + dy, sx = x_[m] + dx;
        bool v = (sy >= 0) & (sy < H) & (sx >= 0) & (sx < W);
        int pix = (b_[m] << lgHW) + (sy << lgW) + sx;
        apc[m] = v ? (actin + (size_t)pix * Cip + 8 * g) : (zp + 8 * g);
      }
    };

    auto prefA_slice = [&](int cg, int cc, short8v (&dst)[GRP][M], bool force) {
      if ((cg & (CPT - 1)) == 0 || force) mkaddr(cg >> lgcpt);
      int kc = (cg & (CPT - 1)) << 5;
#pragma unroll
      for (int m = 0; m < M; ++m)
        dst[cc][m] = *(const short8v*)(apc[m] + kc);
    };

    f32x4 acc[M][N] = {};
    const int rdb = l15 * 32 + ((g ^ ((l15 >> 1) & 3)) * 8);

    short8v aA[GRP][M], aB[GRP][M];

    auto grp_body = [&](int gi, short8v (&aU)[GRP][M], short8v (&aF)[GRP][M]) {
      asm volatile("s_waitcnt vmcnt(%0)" :: "n"(WAITN) : "memory");
      __builtin_amdgcn_s_barrier();
      __builtin_amdgcn_sched_barrier(0);

      const bool more = (gi + 1 < NGRP);
      if (more) stage(gi + 1, (gi + 1) & 1);

      const __hip_bfloat16* bp = &ldsh[(gi & 1) * BUFELEM];
#pragma unroll
      for (int cc = 0; cc < GRP; ++cc) {
        if (more) prefA_slice(kw * NCH + (gi + 1) * GRP + cc, cc, aF, false);
        short8v bh[N], bl[N];
#pragma unroll
        for (int j = 0; j < N; ++j) {
          bh[j] = *(const short8v*)(bp + cc * (R * 32) + j * 512 + rdb);
          bl[j] = *(const short8v*)(bp + cc * (R * 32) + (N * 512) + j * 512 + rdb);
        }
        __builtin_amdgcn_s_setprio(1);
#pragma unroll
        for (int j = 0; j < N; ++j)
#pragma unroll
          for (int m = 0; m < M; ++m) {
            acc[m][j] = __builtin_amdgcn_mfma_f32_16x16x32_bf16(aU[cc][m], bh[j], acc[m][j], 0, 0, 0);
            acc[m][j] = __builtin_amdgcn_mfma_f32_16x16x32_bf16(aU[cc][m], bl[j], acc[m][j], 0, 0, 0);
          }
        __builtin_amdgcn_s_setprio(0);
      }
    };

    stage(0, 0);
#pragma unroll
    for (int cc = 0; cc < GRP; ++cc)
      prefA_slice(kw * NCH + cc, cc, aA, cc == 0);

#pragma unroll
    for (int gi = 0; gi < NGRP; ++gi) {
      if (gi & 1) grp_body(gi, aB, aA);
      else        grp_body(gi, aA, aB);
    }

    if constexpr (SPLIT == 2) {
      asm volatile("s_waitcnt vmcnt(0) lgkmcnt(0)" ::: "memory");
      __builtin_amdgcn_s_barrier();
      float* red = (float*)lds;
      const int tid = wq * 64 + lane;
      if (kw == 1) {
#pragma unroll
        for (int m = 0; m < M; ++m)
#pragma unroll
          for (int j = 0; j < N; ++j)
#pragma unroll
            for (int r = 0; r < 4; ++r)
              red[((m * N + j) * 4 + r) * 256 + tid] = acc[m][j][r];
      }
      asm volatile("s_waitcnt lgkmcnt(0)" ::: "memory");
      __builtin_amdgcn_s_barrier();
      if (kw == 1) return;
#pragma unroll
      for (int m = 0; m < M; ++m)
#pragma unroll
        for (int j = 0; j < N; ++j)
#pragma unroll
          for (int r = 0; r < 4; ++r)
            acc[m][j][r] += red[((m * N + j) * 4 + r) * 256 + tid];
    }

#pragma unroll
    for (int j = 0; j < N; ++j) {
      int c = co0 + j * 16 + l15;
      float ga = bnt[c], mu = bnt[Co + c], va = bnt[2 * Co + c];
      float sc = ga / sqrtf(va + BNEPS);
#pragma unroll
      for (int m = 0; m < M; ++m) {
        int pixb = p0 + m * 16 + 4 * g;
#pragma unroll
        for (int r = 0; r < 4; ++r) {
          size_t idx = (size_t)(pixb + r) * Co + c;
          float bno = (acc[m][j][r] - mu) * sc;
          float mv = LEAK * mem[idx] + bno;
          float s = (mv > THRS) ? 1.0f : 0.0f;
          actout[idx] = __float2bfloat16(s);
          mem[idx] = mv - s;
        }
      }
    }
  } else {
    // ================= 32x32x16 path (M==2, k-major LDS) =================
    static_assert(M == 2 && (N % 2) == 0, "M32 path requires M==2, even N");
    constexpr int NR = N / 2;
    const int l31 = lane & 31, h5 = lane >> 5;

    int b0_, y0_, x0_;
    {
      int rem = p0 & (HW - 1);
      b0_ = p0 >> lgHW;
      y0_ = rem >> lgW;
      x0_ = (rem & (W - 1)) + l31;         // 32 consecutive px stay in one row (W>=32)
    }

    const __hip_bfloat16* apc32;
    auto mkaddr = [&](int tap) {
      int ty = (tap * 11) >> 5;
      int tx = tap - ty * 3;
      int dy = (ty - 1) * dil, dx = (tx - 1) * dil;
      int sy = y0_ + dy, sx = x0_ + dx;
      bool v = (sy >= 0) & (sy < H) & (sx >= 0) & (sx < W);
      int pix = (b0_ << lgHW) + (sy << lgW) + sx;
      apc32 = v ? (actin + (size_t)pix * Cip + 8 * h5) : (zp + 8 * h5);
    };

    auto prefA_slice = [&](int cg, int cc, short8v (&dst)[GRP][2], bool force) {
      if ((cg & (CPT - 1)) == 0 || force) mkaddr(cg >> lgcpt);
      int kc = (cg & (CPT - 1)) << 5;
      dst[cc][0] = *(const short8v*)(apc32 + kc);
      dst[cc][1] = *(const short8v*)(apc32 + kc + 16);
    };

    f32x16 acc[NR] = {};
    short8v aA[GRP][2], aB[GRP][2];
    const int rdco = l31 * 8;                 // elem offset of this lane's co unit

    auto grp_body = [&](int gi, short8v (&aU)[GRP][2], short8v (&aF)[GRP][2]) {
      asm volatile("s_waitcnt vmcnt(%0)" :: "n"(WAITN) : "memory");
      __builtin_amdgcn_s_barrier();
      __builtin_amdgcn_sched_barrier(0);

      const bool more = (gi + 1 < NGRP);
      if (more) stage(gi + 1, (gi + 1) & 1);

      const __hip_bfloat16* bp = &ldsh[(gi & 1) * BUFELEM];
#pragma unroll
      for (int cc = 0; cc < GRP; ++cc) {
        if (more) prefA_slice(kw * NCH + (gi + 1) * GRP + cc, cc, aF, false);
#pragma unroll
        for (int kh = 0; kh < 2; ++kh) {
          // [chunk][half][slot][co]: slot = kh*2 + h5 -> contiguous 512B per half-wave
          const int sb = cc * (R * 32) + (kh * 2 + h5) * (8 * CoB) + rdco;
          short8v bh[NR], bl[NR];
#pragma unroll
          for (int j = 0; j < NR; ++j) {
            bh[j] = *(const short8v*)(bp + sb + j * 256);
            bl[j] = *(const short8v*)(bp + (32 * CoB) + sb + j * 256);
          }
          __builtin_amdgcn_s_setprio(1);
#pragma unroll
          for (int j = 0; j < NR; ++j) {
            acc[j] = __builtin_amdgcn_mfma_f32_32x32x16_bf16(aU[cc][kh], bh[j], acc[j], 0, 0, 0);
            acc[j] = __builtin_amdgcn_mfma_f32_32x32x16_bf16(aU[cc][kh], bl[j], acc[j], 0, 0, 0);
          }
          __builtin_amdgcn_s_setprio(0);
        }
      }
    };

    stage(0, 0);
#pragma unroll
    for (int cc = 0; cc < GRP; ++cc)
      prefA_slice(kw * NCH + cc, cc, aA, cc == 0);

#pragma unroll
    for (int gi = 0; gi < NGRP; ++gi) {
      if (gi & 1) grp_body(gi, aB, aA);
      else        grp_body(gi, aA, aB);
    }

    if constexpr (SPLIT == 2) {
      asm volatile("s_waitcnt vmcnt(0) lgkmcnt(0)" ::: "memory");
      __builtin_amdgcn_s_barrier();
      float* red = (float*)lds;
      const int tid = wq * 64 + lane;
      if (kw == 1) {
#pragma unroll
        for (int j = 0; j < NR; ++j)
#pragma unroll
          for (int r = 0; r < 16; ++r)
            red[(j * 16 + r) * 256 + tid] = acc[j][r];
      }
      asm volatile("s_waitcnt lgkmcnt(0)" ::: "memory");
      __builtin_amdgcn_s_barrier();
      if (kw == 1) return;
#pragma unroll
      for (int j = 0; j < NR; ++j)
#pragma unroll
        for (int r = 0; r < 16; ++r)
          acc[j][r] += red[(j * 16 + r) * 256 + tid];
    }

    // epilogue: D col = lane&31 (co), row = (reg&3)+8*(reg>>2)+4*(lane>>5) (pixel)
#pragma unroll
    for (int j = 0; j < NR; ++j) {
      int c = co0 + j * 32 + l31;
      float ga = bnt[c], mu = bnt[Co + c], va = bnt[2 * Co + c];
      float sc = ga / sqrtf(va + BNEPS);
#pragma unroll
      for (int r = 0; r < 16; ++r) {
        int pixel = p0 + (r & 3) + 8 * (r >> 2) + 4 * h5;
        size_t idx = (size_t)pixel * Co + c;
        float bno = (acc[j][r] - mu) * sc;
        float mv = LEAK * mem[idx] + bno;
        float s = (mv > THRS) ? 1.0f : 0.0f;
        actout[idx] = __float2bfloat16(s);
        mem[idx] = mv - s;
      }
    }
  }
}

// AvgPool(3,2,1) storing SUM (exact ints in bf16); /9 folded into next layer weights.
__global__ void avgpool_sum8(const __hip_bfloat16* __restrict__ in,
                             __hip_bfloat16* __restrict__ out, int C, int H, int W) {
  const int Ho = H >> 1, Wo = W >> 1;
  const int C8 = C >> 3;
  const int n = BB * Ho * Wo * C8;
  int i = blockIdx.x * 256 + threadIdx.x;
  if (i >= n) return;
  int c8 = i % C8; int t = i / C8;
  int xo = t % Wo; t /= Wo;
  int yo = t % Ho; int b = t / Ho;
  const int y0 = 2 * yo - 1, x0 = 2 * xo - 1;
  float s[8] = {0, 0, 0, 0, 0, 0, 0, 0};
#pragma unroll
  for (int dy = 0; dy < 3; ++dy) {
    int iy = y0 + dy;
    if (iy < 0 || iy >= H) continue;
#pragma unroll
    for (int dx = 0; dx < 3; ++dx) {
      int ix = x0 + dx;
      if (ix < 0 || ix >= W) continue;
      short8v v = *(const short8v*)(in + (((size_t)b * H + iy) * W + ix) * C + c8 * 8);
#pragma unroll
      for (int e = 0; e < 8; ++e) {
        __hip_bfloat16_raw raw; raw.x = (unsigned short)v[e];
        s[e] += __bfloat162float(__hip_bfloat16(raw));
      }
    }
  }
  short8v o;
#pragma unroll
  for (int e = 0; e < 8; ++e) {
    __hip_bfloat16_raw raw = __hip_bfloat16_raw(__float2bfloat16(s[e]));
    o[e] = (short)raw.x;
  }
  *(short8v*)(out + (size_t)i * 8) = o;
}

// 1x1 conv 1024->21 @32x32, f32, accumulate into d_out. One wave per (b,pix).
__global__ void out_conv(const __hip_bfloat16* __restrict__ act,  // [B*1024px][1024ch]
                         const float* __restrict__ W8, float* __restrict__ out) {
  int gw = (blockIdx.x * 256 + threadIdx.x) >> 6;  // b*1024 + pix
  int lane = threadIdx.x & 63;
  int b = gw >> 10, pix = gw & 1023;
  const __hip_bfloat16* ap = act + ((size_t)gw << 10);
  float acc[NCLS];
#pragma unroll
  for (int c = 0; c < NCLS; ++c) acc[c] = 0.0f;
  for (int j = 0; j < 16; ++j) {
    int ci = j * 64 + lane;
    float av = __bfloat162float(ap[ci]);
#pragma unroll
    for (int c = 0; c < NCLS; ++c) acc[c] = fmaf(av, W8[c * 1024 + ci], acc[c]);
  }
#pragma unroll
  for (int c = 0; c < NCLS; ++c) {
    float v = acc[c];
    for (int off = 32; off; off >>= 1) v += __shfl_xor(v, off, 64);
    if (lane == 0) out[((size_t)b * NCLS + c) * 1024 + pix] += v;
  }
}

extern "C" void kernel_launch(void* const* d_in, const int* in_sizes, int n_in,
                              void* d_out, int out_size, void* d_ws, size_t ws_size,
                              hipStream_t stream) {
  const float* x = (const float*)d_in[0];
  const float* u = (const float*)d_in[1];
  const float* Wc[9];
  for (int i = 0; i < 9; ++i) Wc[i] = (const float*)d_in[2 + i];
  const float* bn[8];
  for (int i = 0; i < 8; ++i) bn[i] = (const float*)d_in[11 + i];

  const int Ci_[8]  = {3, 64, 64, 128, 128, 256, 256, 256};
  const int Cip_[8] = {8, 64, 64, 128, 128, 256, 256, 256};
  const int Co_[8]  = {64, 64, 128, 128, 256, 256, 256, 1024};
  const int HH_[8]  = {128, 128, 64, 64, 32, 32, 32, 32};
  const float wsc_[8] = {1.f, 1.f, 1.f / 9.f, 1.f, 1.f / 9.f, 1.f, 1.f, 1.f};

  float* ws = (float*)d_ws;
  size_t off = 0;
  auto align8 = [](size_t v) { return (v + 7) & ~(size_t)7; };

  float* memp[8];
  for (int i = 0; i < 8; ++i) {
    memp[i] = ws + off;
    off += (size_t)BB * HH_[i] * HH_[i] * Co_[i];
  }
  __hip_bfloat16* zp = (__hip_bfloat16*)(ws + off);   // zero page (1 KB)
  off += 256;
  const size_t zero_floats = off;                     // mem + zp zeroed each call
  __hip_bfloat16* spk = (__hip_bfloat16*)(ws + off);  // [B*HW][8], fully written each step
  off += (size_t)BB * 16384 * 8 / 2;
  __hip_bfloat16* actA = (__hip_bfloat16*)(ws + off); off += 2097152;
  __hip_bfloat16* actB = (__hip_bfloat16*)(ws + off); off += 2097152;
  __hip_bfloat16* wall[8];
  wall[0] = (__hip_bfloat16*)(ws + off);
  off = align8(off + (size_t)64 * 96);
  for (int i = 1; i < 8; ++i) {
    size_t n = (size_t)Co_[i] * 9 * Cip_[i];
    wall[i] = (__hip_bfloat16*)(ws + off);
    off = align8(off + n);
  }

  zero_f32<<<2048, 256, 0, stream>>>(ws, (int)zero_floats);
  zero_f32<<<(BB * NCLS * 1024 + 255) / 256, 256, 0, stream>>>((float*)d_out, BB * NCLS * 1024);

  wsplit_l0<<<(64 * 96 + 255) / 256, 256, 0, stream>>>(Wc[0], wall[0], wall[0] + 64 * 96);
  for (int i = 1; i < 8; ++i) {
    int n = Co_[i] * 9 * Cip_[i];
    wsplit<<<(n + 255) / 256, 256, 0, stream>>>(Wc[i], wall[i], wall[i] + n,
                                                Co_[i], Ci_[i], Cip_[i], wsc_[i]);
  }

  const size_t uT = (size_t)BB * 3 * 16384;
  for (int t = 0; t < TT; ++t) {
    spike_gen8<<<(BB * 16384 + 255) / 256, 256, 0, stream>>>(x, u + (size_t)t * uT, spk);
    // L0: tap-packed, grid 1024 (4 waves/SIMD), K=96
    gemm_lif_l0<<<1024, 256, 0, stream>>>(spk, wall[0], bn[0] + (size_t)t * 3 * 64, memp[0], actA, zp);
    // L1: 64->64 @128      wave 32x32 (32x32x16 MFMA, k-major LDS), grid 1024
    gemm_lif<2, 2, 3, 2, 1><<<1024, 256, 0, stream>>>(actA, wall[1], bn[1] + (size_t)t * 3 * 64,   memp[1], actB, zp, 64,   14, 7, 1, 9);
    avgpool_sum8<<<(BB * 64 * 64 * 8 + 255) / 256, 256, 0, stream>>>(actB, actA, 64, 128, 128);
    // L2: 64->128 @64 (w/9)  wave 32x32 (32x32x16), split-K x2
    gemm_lif<2, 2, 3, 2, 2><<<512, 512, 0, stream>>>(actA, wall[2], bn[2] + (size_t)t * 3 * 128,  memp[2], actB, zp, 128,  12, 6, 1, 7);
    // L3: 128->128 @64       wave 32x32 (32x32x16), split-K x2
    gemm_lif<2, 2, 3, 4, 2><<<512, 512, 0, stream>>>(actB, wall[3], bn[3] + (size_t)t * 3 * 128,  memp[3], actA, zp, 128,  12, 6, 1, 7);
    avgpool_sum8<<<(BB * 32 * 32 * 16 + 255) / 256, 256, 0, stream>>>(actA, actB, 128, 64, 64);
    // L4: 128->256 @32 (w/9) wave 16x32 (16x16x32), split-K x2
    gemm_lif<1, 2, 3, 4, 2><<<512, 512, 0, stream>>>(actB, wall[4], bn[4] + (size_t)t * 3 * 256,   memp[4], actA, zp, 256,  10, 5, 1, 6);
    // L5: 256->256 @32 dil2  wave 16x32 (16x16x32), split-K x2
    gemm_lif<1, 2, 4, 8, 2><<<512, 512, 0, stream>>>(actA, wall[5], bn[5] + (size_t)t * 3 * 256,   memp[5], actB, zp, 256,  10, 5, 2, 6);
    // L6: 256->256 @32 dil2
    gemm_lif<1, 2, 4, 8, 2><<<512, 512, 0, stream>>>(actB, wall[6], bn[6] + (size_t)t * 3 * 256,   memp[6], actA, zp, 256,  10, 5, 2, 6);
    // L7: 256->1024 @32 dil12  wave 32x64 (32x32x16, NR=2), split-K x2
    gemm_lif<2, 4, 2, 8, 2><<<512, 512, 0, stream>>>(actA, wall[7], bn[7] + (size_t)t * 3 * 1024, memp[7], actB, zp, 1024, 10, 5, 12, 5);
    // output layer accumulation
    out_conv<<<dim3(BB * 1024 / 4), 256, 0, stream>>>(actB, Wc[8], (float*)d_out);
  }
  scale_f32<<<(BB * NCLS * 1024 + 255) / 256, 256, 0, stream>>>((float*)d_out, BB * NCLS * 1024, 1.0f / TT);
}

// Round 17
// 1954.572 us; speedup vs baseline: 1.1489x; 1.1489x over previous
//
#include <hip/hip_runtime.h>
#include <hip/hip_bf16.h>
#include <cstddef>
#include <cstdint>

#define LEAK  0.99f
#define THRS  1.0f
#define BNEPS 1e-4f

static constexpr int TT   = 8;
static constexpr int BB   = 4;
static constexpr int NCLS = 21;

typedef __attribute__((ext_vector_type(8))) short short8v;   // 8 bf16 (MFMA A/B frag)
typedef __attribute__((ext_vector_type(4))) float f32x4;     // 16x16 C/D frag
typedef __attribute__((ext_vector_type(16))) float f32x16;   // 32x32 C/D frag

__global__ void zero_f32(float* __restrict__ p, int n) {
  int i = blockIdx.x * blockDim.x + threadIdx.x;
  int stride = gridDim.x * blockDim.x;
  for (; i < n; i += stride) p[i] = 0.0f;
}

__global__ void scale_f32(float* __restrict__ p, int n, float s) {
  int i = blockIdx.x * blockDim.x + threadIdx.x;
  if (i < n) p[i] *= s;
}

// Row-major split (M==1 layers): [half][co][k], k = tap*Cip + ci.
__global__ void wsplit(const float* __restrict__ Wsrc,
                       __hip_bfloat16* __restrict__ whi, __hip_bfloat16* __restrict__ wlo,
                       int Co, int Ci, int Cip, float scale) {
  const int Kpad = 9 * Cip;
  const int n = Co * Kpad;
  int i = blockIdx.x * 256 + threadIdx.x;
  if (i >= n) return;
  int co = i / Kpad, k = i - co * Kpad;
  int tap = k / Cip, ci = k - tap * Cip;
  float w = 0.0f;
  if (ci < Ci) w = Wsrc[((size_t)co * Ci + ci) * 9 + tap] * scale;
  __hip_bfloat16 h = __float2bfloat16(w);
  float r = w - __bfloat162float(h);
  whi[i] = h;
  wlo[i] = __float2bfloat16(r);
}

// K-major split (M==2 layers): [half][k>>3][Co][8] -> staging of [slot][co] tiles
// is CONTIGUOUS in global memory (coalesced global_load_lds) while the LDS
// layout is k-major (conflict-free ds_read for the 32x32 MFMA B operand).
__global__ void wsplit_kmaj(const float* __restrict__ Wsrc,
                            __hip_bfloat16* __restrict__ whi, __hip_bfloat16* __restrict__ wlo,
                            int Co, int Ci, int Cip, float scale) {
  const int Kpad = 9 * Cip;
  const int n = Co * Kpad;
  int i = blockIdx.x * 256 + threadIdx.x;
  if (i >= n) return;
  int co = i / Kpad, k = i - co * Kpad;
  int tap = k / Cip, ci = k - tap * Cip;
  float w = 0.0f;
  if (ci < Ci) w = Wsrc[((size_t)co * Ci + ci) * 9 + tap] * scale;
  __hip_bfloat16 h = __float2bfloat16(w);
  float r = w - __bfloat162float(h);
  size_t o = ((size_t)(k >> 3) * Co + co) * 8 + (k & 7);
  whi[o] = h;
  wlo[o] = __float2bfloat16(r);
}

// L0 packed weights: k = slot*8 + ci, 12 slots (9 taps + 3 zero), 8ch (3 real).
__global__ void wsplit_l0(const float* __restrict__ W0,
                          __hip_bfloat16* __restrict__ whi, __hip_bfloat16* __restrict__ wlo) {
  int i = blockIdx.x * 256 + threadIdx.x;      // co*96 + k
  if (i >= 64 * 96) return;
  int co = i / 96, k = i - co * 96;
  int slot = k >> 3, ci = k & 7;
  float w = 0.0f;
  if (slot < 9 && ci < 3) w = W0[((size_t)co * 3 + ci) * 9 + slot];
  __hip_bfloat16 h = __float2bfloat16(w);
  float r = w - __bfloat162float(h);
  whi[i] = h;
  wlo[i] = __float2bfloat16(r);
}

// Poisson generator -> channel-last [B*HW][8] (ch 3..7 zero), one 16B store/px.
__global__ void spike_gen8(const float* __restrict__ x, const float* __restrict__ u,
                           __hip_bfloat16* __restrict__ spk) {
  const int HW = 128 * 128;
  int i = blockIdx.x * 256 + threadIdx.x;  // b*HW + hw
  if (i >= BB * HW) return;
  int b = i / HW, hw = i - b * HW;
  short8v o = {};
#pragma unroll
  for (int c = 0; c < 3; ++c) {
    float xv = x[((size_t)b * 3 + c) * HW + hw];
    float uv = u[((size_t)b * 3 + c) * HW + hw];
    float ax = fabsf(xv);
    float sg = (xv > 0.0f) ? 1.0f : ((xv < 0.0f) ? -1.0f : 0.0f);
    float s  = (uv <= ax) ? sg : 0.0f;
    __hip_bfloat16_raw raw = __hip_bfloat16_raw(__float2bfloat16(s));
    o[c] = (short)raw.x;
  }
  *(short8v*)(spk + (size_t)i * 8) = o;
}

// L0 dedicated (r13): tap-packed implicit GEMM, K = 96 (12 slots x 8ch), 3 chunks.
__global__ __launch_bounds__(256) void gemm_lif_l0(
    const __hip_bfloat16* __restrict__ spk,   // [B*HW][8]
    const __hip_bfloat16* __restrict__ wsp,   // [2][64][96] hi, lo
    const float* __restrict__ bnt, float* __restrict__ mem,
    __hip_bfloat16* __restrict__ actout,
    const __hip_bfloat16* __restrict__ zp) {
  constexpr int M = 2, Co = 64, Kpk = 96, HW = 16384, H = 128, W = 128;
  __shared__ __hip_bfloat16 lds[3 * 64 * 32];
  const int lane = threadIdx.x & 63, wid = threadIdx.x >> 6;
  const int l15 = lane & 15, g = lane >> 4;

  const int nb = gridDim.x;
  const int flat = blockIdx.x;
  const int swz = (flat & 7) * (nb >> 3) + (flat >> 3);
  const int bx = swz & 511, by = swz >> 9;
  const int p0 = (bx * 4 + wid) * 32;
  const int co0 = by * 32;

  int b_[M], y_[M], x_[M];
#pragma unroll
  for (int m = 0; m < M; ++m) {
    int pb = p0 + m * 16;
    b_[m] = pb >> 14;
    int rem = pb & (HW - 1);
    y_[m] = rem >> 7;
    x_[m] = (rem & 127) + l15;
  }

  unsigned sgb[3];
#pragma unroll
  for (int i = 0; i < 3; ++i) {
    int f = wid * 48 + i * 16 + (lane >> 2);
    int cc = f >> 6;
    int r  = f & 63;
    int half = r >> 5;
    int co   = r & 31;
    int slot = (lane & 3) ^ ((co >> 1) & 3);
    sgb[i] = (unsigned)half * Co * Kpk + (unsigned)(co0 + co) * Kpk + slot * 8 + cc * 32;
  }
#pragma unroll
  for (int i = 0; i < 3; ++i) {
    const __hip_bfloat16* gp = wsp + sgb[i];
    __hip_bfloat16* lp = &lds[(wid * 48 + i * 16) * 32];
    __builtin_amdgcn_global_load_lds(
        (const __attribute__((address_space(1))) void*)gp,
        (__attribute__((address_space(3))) void*)lp, 16, 0, 0);
  }

  short8v aA[3][M];
#pragma unroll
  for (int c = 0; c < 3; ++c) {
    int tap = c * 4 + g;
    int ty = (tap * 11) >> 5;
    int tx = tap - ty * 3;
    int dy = ty - 1, dx = tx - 1;
#pragma unroll
    for (int m = 0; m < M; ++m) {
      int sy = y_[m] + dy, sx = x_[m] + dx;
      bool v = (tap < 9) & (sy >= 0) & (sy < H) & (sx >= 0) & (sx < W);
      int pix = (b_[m] << 14) + (sy << 7) + sx;
      const __hip_bfloat16* ap = v ? (spk + (size_t)pix * 8) : zp;
      aA[c][m] = *(const short8v*)ap;
    }
  }

  asm volatile("s_waitcnt vmcnt(%0)" :: "n"(6) : "memory");
  __builtin_amdgcn_s_barrier();
  __builtin_amdgcn_sched_barrier(0);

  f32x4 acc[M][2] = {};
  const int rdb = l15 * 32 + ((g ^ ((l15 >> 1) & 3)) * 8);
#pragma unroll
  for (int c = 0; c < 3; ++c) {
    short8v bh[2], bl[2];
#pragma unroll
    for (int j = 0; j < 2; ++j) {
      bh[j] = *(const short8v*)(&lds[c * 2048] + j * 512 + rdb);
      bl[j] = *(const short8v*)(&lds[c * 2048] + 1024 + j * 512 + rdb);
    }
    __builtin_amdgcn_s_setprio(1);
#pragma unroll
    for (int j = 0; j < 2; ++j)
#pragma unroll
      for (int m = 0; m < M; ++m) {
        acc[m][j] = __builtin_amdgcn_mfma_f32_16x16x32_bf16(aA[c][m], bh[j], acc[m][j], 0, 0, 0);
        acc[m][j] = __builtin_amdgcn_mfma_f32_16x16x32_bf16(aA[c][m], bl[j], acc[m][j], 0, 0, 0);
      }
    __builtin_amdgcn_s_setprio(0);
  }

#pragma unroll
  for (int j = 0; j < 2; ++j) {
    int c = co0 + j * 16 + l15;
    float ga = bnt[c], mu = bnt[Co + c], va = bnt[2 * Co + c];
    float sc = ga / sqrtf(va + BNEPS);
#pragma unroll
    for (int m = 0; m < M; ++m) {
      int pixb = p0 + m * 16 + 4 * g;
#pragma unroll
      for (int r = 0; r < 4; ++r) {
        size_t idx = (size_t)(pixb + r) * Co + c;
        float bno = (acc[m][j][r] - mu) * sc;
        float mv = LEAK * mem[idx] + bno;
        float s = (mv > THRS) ? 1.0f : 0.0f;
        actout[idx] = __float2bfloat16(s);
        mem[idx] = mv - s;
      }
    }
  }
}

// Generic implicit-GEMM conv3x3(pad==dil) + BN + LIF (r12/r13 pipeline).
// M==1: 16x16x32 MFMA, row-major LDS + slot swizzle (r13 verbatim).
// M==2: 32x32x16 MFMA, k-major LDS [chunk][half][slot4][co] AND k-major GLOBAL
//       weights [half][k>>3][Co][8]: staging coalesced (consecutive lanes ->
//       consecutive co -> contiguous), B-reads contiguous 512B (0 conflicts).
template<int M, int N, int GRP, int CPT, int SPLIT>
__global__ __launch_bounds__(SPLIT * 256, 4) void gemm_lif(
    const __hip_bfloat16* __restrict__ actin,
    const __hip_bfloat16* __restrict__ wsp,
    const float* __restrict__ bnt,               // [3][Co] for this timestep
    float* __restrict__ mem, __hip_bfloat16* __restrict__ actout,
    const __hip_bfloat16* __restrict__ zp,
    int Co, int lgHW, int lgW, int dil, int lgGX) {
  constexpr int NW = 4;
  constexpr int Cip = CPT * 32;
  constexpr int Kpad = 9 * Cip;
  constexpr int lgcpt = (CPT == 1) ? 0 : (CPT == 2) ? 1 : (CPT == 4) ? 2 : 3;
  constexpr int R  = N * 32;                 // 64B rows per chunk (hi+lo)
  constexpr int lgR = (N == 1) ? 5 : ((N == 2) ? 6 : 7);
  constexpr int CoB = 16 * N;                // co per block
  constexpr int BUFROWS = GRP * R;
  constexpr int BUFELEM = BUFROWS * 32;
  constexpr int INSTS = BUFROWS / (16 * NW);
  constexpr int AM = M * GRP;
  constexpr int WAITN = AM;
  constexpr int NCH = (9 * CPT) / SPLIT;
  constexpr int NGRP = NCH / GRP;
  static_assert(NCH % GRP == 0, "group must divide per-half chunk count");
  __shared__ __hip_bfloat16 lds[SPLIT * 2 * BUFELEM];

  const int HW = 1 << lgHW, H = HW >> lgW, W = 1 << lgW;
  const unsigned CoKpad = (unsigned)Co * Kpad;
  const int lane = threadIdx.x & 63, wid = threadIdx.x >> 6;
  const int kw = wid >> 2;
  const int wq = wid & 3;
  __hip_bfloat16* ldsh = lds + kw * 2 * BUFELEM;

  const int nb = gridDim.x;
  const int flat = blockIdx.x;
  const int swz = (flat & 7) * (nb >> 3) + (flat >> 3);
  const int bx = swz & ((1 << lgGX) - 1);
  const int by = swz >> lgGX;
  const int p0  = (bx * NW + wq) * (M * 16);
  const int co0 = by * (N * 16);

  const unsigned kbase = (unsigned)kw * (NCH * 32);
  unsigned sgb[INSTS];
  unsigned GSTEP;                              // global elem advance per group
  if constexpr (M == 1) {
    GSTEP = GRP * 32;
    // row-major [half][co][k], slot XOR-swizzled on global src
#pragma unroll
    for (int i = 0; i < INSTS; ++i) {
      int f  = wq * (BUFROWS / NW) + i * 16 + (lane >> 2);
      int cc = f >> lgR;
      int r  = f & (R - 1);
      int half = r >> (lgR - 1);
      int co   = r & (16 * N - 1);
      int slot = (lane & 3) ^ ((co >> 1) & 3);
      sgb[i] = (unsigned)half * CoKpad + (unsigned)(co0 + co) * Kpad + slot * 8
             + cc * 32 + kbase;
    }
  } else {
    GSTEP = (unsigned)GRP * 32 * Co;           // k advances GRP*32 -> k8 by GRP*4
    // k-major global [half][k8][Co][8]; unit (cc,hf,sl,co) -> contiguous in co
#pragma unroll
    for (int i = 0; i < INSTS; ++i) {
      int u  = wq * (INSTS * 64) + i * 64 + lane;   // 16B unit within group buffer
      int cc = u / (8 * CoB);                        // units per chunk = 8*CoB
      int uc = u - cc * (8 * CoB);
      int hf = uc / (4 * CoB);
      int rm = uc - hf * (4 * CoB);
      int sl = rm / CoB;
      int col = rm - sl * CoB;
      unsigned k8 = (kbase >> 3) + cc * 4 + sl;
      sgb[i] = (unsigned)hf * CoKpad + (k8 * (unsigned)Co + co0 + col) * 8;
    }
  }

  auto stage = [&](int gl, int buf) {
#pragma unroll
    for (int i = 0; i < INSTS; ++i) {
      const __hip_bfloat16* gp = wsp + sgb[i] + (unsigned)gl * GSTEP;
      __hip_bfloat16* lp = &ldsh[buf * BUFELEM + (wq * (BUFROWS / NW) + i * 16) * 32];
      __builtin_amdgcn_global_load_lds(
          (const __attribute__((address_space(1))) void*)gp,
          (__attribute__((address_space(3))) void*)lp, 16, 0, 0);
    }
  };

  if constexpr (M == 1) {
    // ================= 16x16x32 path (r13 verbatim) =================
    const int l15 = lane & 15, g = lane >> 4;

    int b_[M], y_[M], x_[M];
#pragma unroll
    for (int m = 0; m < M; ++m) {
      int pb = p0 + m * 16;
      b_[m] = pb >> lgHW;
      int rem = pb & (HW - 1);
      y_[m] = rem >> lgW;
      x_[m] = (rem & (W - 1)) + l15;
    }

    const __hip_bfloat16* apc[M];
    auto mkaddr = [&](int tap) {
      int ty = (tap * 11) >> 5;
      int tx = tap - ty * 3;
      int dy = (ty - 1) * dil, dx = (tx - 1) * dil;
#pragma unroll
      for (int m = 0; m < M; ++m) {
        int sy = y_[m] + dy, sx = x_[m] + dx;
        bool v = (sy >= 0) & (sy < H) & (sx >= 0) & (sx < W);
        int pix = (b_[m] << lgHW) + (sy << lgW) + sx;
        apc[m] = v ? (actin + (size_t)pix * Cip + 8 * g) : (zp + 8 * g);
      }
    };

    auto prefA_slice = [&](int cg, int cc, short8v (&dst)[GRP][M], bool force) {
      if ((cg & (CPT - 1)) == 0 || force) mkaddr(cg >> lgcpt);
      int kc = (cg & (CPT - 1)) << 5;
#pragma unroll
      for (int m = 0; m < M; ++m)
        dst[cc][m] = *(const short8v*)(apc[m] + kc);
    };

    f32x4 acc[M][N] = {};
    const int rdb = l15 * 32 + ((g ^ ((l15 >> 1) & 3)) * 8);

    short8v aA[GRP][M], aB[GRP][M];

    auto grp_body = [&](int gi, short8v (&aU)[GRP][M], short8v (&aF)[GRP][M]) {
      asm volatile("s_waitcnt vmcnt(%0)" :: "n"(WAITN) : "memory");
      __builtin_amdgcn_s_barrier();
      __builtin_amdgcn_sched_barrier(0);

      const bool more = (gi + 1 < NGRP);
      if (more) stage(gi + 1, (gi + 1) & 1);

      const __hip_bfloat16* bp = &ldsh[(gi & 1) * BUFELEM];
#pragma unroll
      for (int cc = 0; cc < GRP; ++cc) {
        if (more) prefA_slice(kw * NCH + (gi + 1) * GRP + cc, cc, aF, false);
        short8v bh[N], bl[N];
#pragma unroll
        for (int j = 0; j < N; ++j) {
          bh[j] = *(const short8v*)(bp + cc * (R * 32) + j * 512 + rdb);
          bl[j] = *(const short8v*)(bp + cc * (R * 32) + (N * 512) + j * 512 + rdb);
        }
        __builtin_amdgcn_s_setprio(1);
#pragma unroll
        for (int j = 0; j < N; ++j)
#pragma unroll
          for (int m = 0; m < M; ++m) {
            acc[m][j] = __builtin_amdgcn_mfma_f32_16x16x32_bf16(aU[cc][m], bh[j], acc[m][j], 0, 0, 0);
            acc[m][j] = __builtin_amdgcn_mfma_f32_16x16x32_bf16(aU[cc][m], bl[j], acc[m][j], 0, 0, 0);
          }
        __builtin_amdgcn_s_setprio(0);
      }
    };

    stage(0, 0);
#pragma unroll
    for (int cc = 0; cc < GRP; ++cc)
      prefA_slice(kw * NCH + cc, cc, aA, cc == 0);

#pragma unroll
    for (int gi = 0; gi < NGRP; ++gi) {
      if (gi & 1) grp_body(gi, aB, aA);
      else        grp_body(gi, aA, aB);
    }

    if constexpr (SPLIT == 2) {
      asm volatile("s_waitcnt vmcnt(0) lgkmcnt(0)" ::: "memory");
      __builtin_amdgcn_s_barrier();
      float* red = (float*)lds;
      const int tid = wq * 64 + lane;
      if (kw == 1) {
#pragma unroll
        for (int m = 0; m < M; ++m)
#pragma unroll
          for (int j = 0; j < N; ++j)
#pragma unroll
            for (int r = 0; r < 4; ++r)
              red[((m * N + j) * 4 + r) * 256 + tid] = acc[m][j][r];
      }
      asm volatile("s_waitcnt lgkmcnt(0)" ::: "memory");
      __builtin_amdgcn_s_barrier();
      if (kw == 1) return;
#pragma unroll
      for (int m = 0; m < M; ++m)
#pragma unroll
        for (int j = 0; j < N; ++j)
#pragma unroll
          for (int r = 0; r < 4; ++r)
            acc[m][j][r] += red[((m * N + j) * 4 + r) * 256 + tid];
    }

#pragma unroll
    for (int j = 0; j < N; ++j) {
      int c = co0 + j * 16 + l15;
      float ga = bnt[c], mu = bnt[Co + c], va = bnt[2 * Co + c];
      float sc = ga / sqrtf(va + BNEPS);
#pragma unroll
      for (int m = 0; m < M; ++m) {
        int pixb = p0 + m * 16 + 4 * g;
#pragma unroll
        for (int r = 0; r < 4; ++r) {
          size_t idx = (size_t)(pixb + r) * Co + c;
          float bno = (acc[m][j][r] - mu) * sc;
          float mv = LEAK * mem[idx] + bno;
          float s = (mv > THRS) ? 1.0f : 0.0f;
          actout[idx] = __float2bfloat16(s);
          mem[idx] = mv - s;
        }
      }
    }
  } else {
    // ================= 32x32x16 path (M==2, k-major LDS + global) =================
    static_assert(M == 2 && (N % 2) == 0, "M32 path requires M==2, even N");
    constexpr int NR = N / 2;
    const int l31 = lane & 31, h5 = lane >> 5;

    int b0_, y0_, x0_;
    {
      int rem = p0 & (HW - 1);
      b0_ = p0 >> lgHW;
      y0_ = rem >> lgW;
      x0_ = (rem & (W - 1)) + l31;         // 32 consecutive px stay in one row (W>=32)
    }

    const __hip_bfloat16* apc32;
    auto mkaddr = [&](int tap) {
      int ty = (tap * 11) >> 5;
      int tx = tap - ty * 3;
      int dy = (ty - 1) * dil, dx = (tx - 1) * dil;
      int sy = y0_ + dy, sx = x0_ + dx;
      bool v = (sy >= 0) & (sy < H) & (sx >= 0) & (sx < W);
      int pix = (b0_ << lgHW) + (sy << lgW) + sx;
      apc32 = v ? (actin + (size_t)pix * Cip + 8 * h5) : (zp + 8 * h5);
    };

    auto prefA_slice = [&](int cg, int cc, short8v (&dst)[GRP][2], bool force) {
      if ((cg & (CPT - 1)) == 0 || force) mkaddr(cg >> lgcpt);
      int kc = (cg & (CPT - 1)) << 5;
      dst[cc][0] = *(const short8v*)(apc32 + kc);
      dst[cc][1] = *(const short8v*)(apc32 + kc + 16);
    };

    f32x16 acc[NR] = {};
    short8v aA[GRP][2], aB[GRP][2];
    const int rdco = l31 * 8;                 // elem offset of this lane's co unit

    auto grp_body = [&](int gi, short8v (&aU)[GRP][2], short8v (&aF)[GRP][2]) {
      asm volatile("s_waitcnt vmcnt(%0)" :: "n"(WAITN) : "memory");
      __builtin_amdgcn_s_barrier();
      __builtin_amdgcn_sched_barrier(0);

      const bool more = (gi + 1 < NGRP);
      if (more) stage(gi + 1, (gi + 1) & 1);

      const __hip_bfloat16* bp = &ldsh[(gi & 1) * BUFELEM];
#pragma unroll
      for (int cc = 0; cc < GRP; ++cc) {
        if (more) prefA_slice(kw * NCH + (gi + 1) * GRP + cc, cc, aF, false);
#pragma unroll
        for (int kh = 0; kh < 2; ++kh) {
          // [chunk][half][slot][co]: slot = kh*2 + h5 -> contiguous 512B per half-wave
          const int sb = cc * (R * 32) + (kh * 2 + h5) * (8 * CoB) + rdco;
          short8v bh[NR], bl[NR];
#pragma unroll
          for (int j = 0; j < NR; ++j) {
            bh[j] = *(const short8v*)(bp + sb + j * 256);
            bl[j] = *(const short8v*)(bp + (32 * CoB) + sb + j * 256);
          }
          __builtin_amdgcn_s_setprio(1);
#pragma unroll
          for (int j = 0; j < NR; ++j) {
            acc[j] = __builtin_amdgcn_mfma_f32_32x32x16_bf16(aU[cc][kh], bh[j], acc[j], 0, 0, 0);
            acc[j] = __builtin_amdgcn_mfma_f32_32x32x16_bf16(aU[cc][kh], bl[j], acc[j], 0, 0, 0);
          }
          __builtin_amdgcn_s_setprio(0);
        }
      }
    };

    stage(0, 0);
#pragma unroll
    for (int cc = 0; cc < GRP; ++cc)
      prefA_slice(kw * NCH + cc, cc, aA, cc == 0);

#pragma unroll
    for (int gi = 0; gi < NGRP; ++gi) {
      if (gi & 1) grp_body(gi, aB, aA);
      else        grp_body(gi, aA, aB);
    }

    if constexpr (SPLIT == 2) {
      asm volatile("s_waitcnt vmcnt(0) lgkmcnt(0)" ::: "memory");
      __builtin_amdgcn_s_barrier();
      float* red = (float*)lds;
      const int tid = wq * 64 + lane;
      if (kw == 1) {
#pragma unroll
        for (int j = 0; j < NR; ++j)
#pragma unroll
          for (int r = 0; r < 16; ++r)
            red[(j * 16 + r) * 256 + tid] = acc[j][r];
      }
      asm volatile("s_waitcnt lgkmcnt(0)" ::: "memory");
      __builtin_amdgcn_s_barrier();
      if (kw == 1) return;
#pragma unroll
      for (int j = 0; j < NR; ++j)
#pragma unroll
        for (int r = 0; r < 16; ++r)
          acc[j][r] += red[(j * 16 + r) * 256 + tid];
    }

    // epilogue: D col = lane&31 (co), row = (reg&3)+8*(reg>>2)+4*(lane>>5) (pixel)
#pragma unroll
    for (int j = 0; j < NR; ++j) {
      int c = co0 + j * 32 + l31;
      float ga = bnt[c], mu = bnt[Co + c], va = bnt[2 * Co + c];
      float sc = ga / sqrtf(va + BNEPS);
#pragma unroll
      for (int r = 0; r < 16; ++r) {
        int pixel = p0 + (r & 3) + 8 * (r >> 2) + 4 * h5;
        size_t idx = (size_t)pixel * Co + c;
        float bno = (acc[j][r] - mu) * sc;
        float mv = LEAK * mem[idx] + bno;
        float s = (mv > THRS) ? 1.0f : 0.0f;
        actout[idx] = __float2bfloat16(s);
        mem[idx] = mv - s;
      }
    }
  }
}

// AvgPool(3,2,1) storing SUM (exact ints in bf16); /9 folded into next layer weights.
__global__ void avgpool_sum8(const __hip_bfloat16* __restrict__ in,
                             __hip_bfloat16* __restrict__ out, int C, int H, int W) {
  const int Ho = H >> 1, Wo = W >> 1;
  const int C8 = C >> 3;
  const int n = BB * Ho * Wo * C8;
  int i = blockIdx.x * 256 + threadIdx.x;
  if (i >= n) return;
  int c8 = i % C8; int t = i / C8;
  int xo = t % Wo; t /= Wo;
  int yo = t % Ho; int b = t / Ho;
  const int y0 = 2 * yo - 1, x0 = 2 * xo - 1;
  float s[8] = {0, 0, 0, 0, 0, 0, 0, 0};
#pragma unroll
  for (int dy = 0; dy < 3; ++dy) {
    int iy = y0 + dy;
    if (iy < 0 || iy >= H) continue;
#pragma unroll
    for (int dx = 0; dx < 3; ++dx) {
      int ix = x0 + dx;
      if (ix < 0 || ix >= W) continue;
      short8v v = *(const short8v*)(in + (((size_t)b * H + iy) * W + ix) * C + c8 * 8);
#pragma unroll
      for (int e = 0; e < 8; ++e) {
        __hip_bfloat16_raw raw; raw.x = (unsigned short)v[e];
        s[e] += __bfloat162float(__hip_bfloat16(raw));
      }
    }
  }
  short8v o;
#pragma unroll
  for (int e = 0; e < 8; ++e) {
    __hip_bfloat16_raw raw = __hip_bfloat16_raw(__float2bfloat16(s[e]));
    o[e] = (short)raw.x;
  }
  *(short8v*)(out + (size_t)i * 8) = o;
}

// 1x1 conv 1024->21 @32x32, f32, accumulate into d_out. One wave per (b,pix).
__global__ void out_conv(const __hip_bfloat16* __restrict__ act,  // [B*1024px][1024ch]
                         const float* __restrict__ W8, float* __restrict__ out) {
  int gw = (blockIdx.x * 256 + threadIdx.x) >> 6;  // b*1024 + pix
  int lane = threadIdx.x & 63;
  int b = gw >> 10, pix = gw & 1023;
  const __hip_bfloat16* ap = act + ((size_t)gw << 10);
  float acc[NCLS];
#pragma unroll
  for (int c = 0; c < NCLS; ++c) acc[c] = 0.0f;
  for (int j = 0; j < 16; ++j) {
    int ci = j * 64 + lane;
    float av = __bfloat162float(ap[ci]);
#pragma unroll
    for (int c = 0; c < NCLS; ++c) acc[c] = fmaf(av, W8[c * 1024 + ci], acc[c]);
  }
#pragma unroll
  for (int c = 0; c < NCLS; ++c) {
    float v = acc[c];
    for (int off = 32; off; off >>= 1) v += __shfl_xor(v, off, 64);
    if (lane == 0) out[((size_t)b * NCLS + c) * 1024 + pix] += v;
  }
}

extern "C" void kernel_launch(void* const* d_in, const int* in_sizes, int n_in,
                              void* d_out, int out_size, void* d_ws, size_t ws_size,
                              hipStream_t stream) {
  const float* x = (const float*)d_in[0];
  const float* u = (const float*)d_in[1];
  const float* Wc[9];
  for (int i = 0; i < 9; ++i) Wc[i] = (const float*)d_in[2 + i];
  const float* bn[8];
  for (int i = 0; i < 8; ++i) bn[i] = (const float*)d_in[11 + i];

  const int Ci_[8]  = {3, 64, 64, 128, 128, 256, 256, 256};
  const int Cip_[8] = {8, 64, 64, 128, 128, 256, 256, 256};
  const int Co_[8]  = {64, 64, 128, 128, 256, 256, 256, 1024};
  const int HH_[8]  = {128, 128, 64, 64, 32, 32, 32, 32};
  const float wsc_[8] = {1.f, 1.f, 1.f / 9.f, 1.f, 1.f / 9.f, 1.f, 1.f, 1.f};
  const bool kmaj_[8] = {false, true, true, true, false, false, false, true};

  float* ws = (float*)d_ws;
  size_t off = 0;
  auto align8 = [](size_t v) { return (v + 7) & ~(size_t)7; };

  float* memp[8];
  for (int i = 0; i < 8; ++i) {
    memp[i] = ws + off;
    off += (size_t)BB * HH_[i] * HH_[i] * Co_[i];
  }
  __hip_bfloat16* zp = (__hip_bfloat16*)(ws + off);   // zero page (1 KB)
  off += 256;
  const size_t zero_floats = off;                     // mem + zp zeroed each call
  __hip_bfloat16* spk = (__hip_bfloat16*)(ws + off);  // [B*HW][8], fully written each step
  off += (size_t)BB * 16384 * 8 / 2;
  __hip_bfloat16* actA = (__hip_bfloat16*)(ws + off); off += 2097152;
  __hip_bfloat16* actB = (__hip_bfloat16*)(ws + off); off += 2097152;
  __hip_bfloat16* wall[8];
  wall[0] = (__hip_bfloat16*)(ws + off);
  off = align8(off + (size_t)64 * 96);
  for (int i = 1; i < 8; ++i) {
    size_t n = (size_t)Co_[i] * 9 * Cip_[i];
    wall[i] = (__hip_bfloat16*)(ws + off);
    off = align8(off + n);
  }

  zero_f32<<<2048, 256, 0, stream>>>(ws, (int)zero_floats);
  zero_f32<<<(BB * NCLS * 1024 + 255) / 256, 256, 0, stream>>>((float*)d_out, BB * NCLS * 1024);

  wsplit_l0<<<(64 * 96 + 255) / 256, 256, 0, stream>>>(Wc[0], wall[0], wall[0] + 64 * 96);
  for (int i = 1; i < 8; ++i) {
    int n = Co_[i] * 9 * Cip_[i];
    if (kmaj_[i])
      wsplit_kmaj<<<(n + 255) / 256, 256, 0, stream>>>(Wc[i], wall[i], wall[i] + n,
                                                       Co_[i], Ci_[i], Cip_[i], wsc_[i]);
    else
      wsplit<<<(n + 255) / 256, 256, 0, stream>>>(Wc[i], wall[i], wall[i] + n,
                                                  Co_[i], Ci_[i], Cip_[i], wsc_[i]);
  }

  const size_t uT = (size_t)BB * 3 * 16384;
  for (int t = 0; t < TT; ++t) {
    spike_gen8<<<(BB * 16384 + 255) / 256, 256, 0, stream>>>(x, u + (size_t)t * uT, spk);
    // L0: tap-packed, grid 1024 (4 waves/SIMD), K=96
    gemm_lif_l0<<<1024, 256, 0, stream>>>(spk, wall[0], bn[0] + (size_t)t * 3 * 64, memp[0], actA, zp);
    // L1: 64->64 @128      wave 32x32 (32x32x16, k-major), grid 1024
    gemm_lif<2, 2, 3, 2, 1><<<1024, 256, 0, stream>>>(actA, wall[1], bn[1] + (size_t)t * 3 * 64,   memp[1], actB, zp, 64,   14, 7, 1, 9);
    avgpool_sum8<<<(BB * 64 * 64 * 8 + 255) / 256, 256, 0, stream>>>(actB, actA, 64, 128, 128);
    // L2: 64->128 @64 (w/9)  wave 32x32 (32x32x16, k-major), split-K x2
    gemm_lif<2, 2, 3, 2, 2><<<512, 512, 0, stream>>>(actA, wall[2], bn[2] + (size_t)t * 3 * 128,  memp[2], actB, zp, 128,  12, 6, 1, 7);
    // L3: 128->128 @64       wave 32x32 (32x32x16, k-major), split-K x2
    gemm_lif<2, 2, 3, 4, 2><<<512, 512, 0, stream>>>(actB, wall[3], bn[3] + (size_t)t * 3 * 128,  memp[3], actA, zp, 128,  12, 6, 1, 7);
    avgpool_sum8<<<(BB * 32 * 32 * 16 + 255) / 256, 256, 0, stream>>>(actA, actB, 128, 64, 64);
    // L4: 128->256 @32 (w/9) wave 16x32 (16x16x32), split-K x2
    gemm_lif<1, 2, 3, 4, 2><<<512, 512, 0, stream>>>(actB, wall[4], bn[4] + (size_t)t * 3 * 256,   memp[4], actA, zp, 256,  10, 5, 1, 6);
    // L5: 256->256 @32 dil2  wave 16x32 (16x16x32), split-K x2
    gemm_lif<1, 2, 4, 8, 2><<<512, 512, 0, stream>>>(actA, wall[5], bn[5] + (size_t)t * 3 * 256,   memp[5], actB, zp, 256,  10, 5, 2, 6);
    // L6: 256->256 @32 dil2
    gemm_lif<1, 2, 4, 8, 2><<<512, 512, 0, stream>>>(actB, wall[6], bn[6] + (size_t)t * 3 * 256,   memp[6], actA, zp, 256,  10, 5, 2, 6);
    // L7: 256->1024 @32 dil12  wave 32x64 (32x32x16, k-major, NR=2), split-K x2
    gemm_lif<2, 4, 2, 8, 2><<<512, 512, 0, stream>>>(actA, wall[7], bn[7] + (size_t)t * 3 * 1024, memp[7], actB, zp, 1024, 10, 5, 12, 5);
    // output layer accumulation
    out_conv<<<dim3(BB * 1024 / 4), 256, 0, stream>>>(actB, Wc[8], (float*)d_out);
  }
  scale_f32<<<(BB * NCLS * 1024 + 255) / 256, 256, 0, stream>>>((float*)d_out, BB * NCLS * 1024, 1.0f / TT);
}

// Round 18
// 1896.171 us; speedup vs baseline: 1.1842x; 1.0308x over previous
//
#include <hip/hip_runtime.h>
#include <hip/hip_bf16.h>
#include <cstddef>
#include <cstdint>

#define LEAK  0.99f
#define THRS  1.0f
#define BNEPS 1e-4f

static constexpr int TT   = 8;
static constexpr int BB   = 4;
static constexpr int NCLS = 21;

typedef __attribute__((ext_vector_type(8))) short short8v;   // 8 bf16 (MFMA A/B frag)
typedef __attribute__((ext_vector_type(4))) float f32x4;     // MFMA C/D frag

__global__ void zero_f32(float* __restrict__ p, int n) {
  int i = blockIdx.x * blockDim.x + threadIdx.x;
  int stride = gridDim.x * blockDim.x;
  for (; i < n; i += stride) p[i] = 0.0f;
}

__global__ void scale_f32(float* __restrict__ p, int n, float s) {
  int i = blockIdx.x * blockDim.x + threadIdx.x;
  if (i < n) p[i] *= s;
}

// Split f32 weights (scaled) into hi+lo bf16, reordered to k = tap*Cip + ci.
__global__ void wsplit(const float* __restrict__ Wsrc,
                       __hip_bfloat16* __restrict__ whi, __hip_bfloat16* __restrict__ wlo,
                       int Co, int Ci, int Cip, float scale) {
  const int Kpad = 9 * Cip;
  const int n = Co * Kpad;
  int i = blockIdx.x * 256 + threadIdx.x;
  if (i >= n) return;
  int co = i / Kpad, k = i - co * Kpad;
  int tap = k / Cip, ci = k - tap * Cip;
  float w = 0.0f;
  if (ci < Ci) w = Wsrc[((size_t)co * Ci + ci) * 9 + tap] * scale;
  __hip_bfloat16 h = __float2bfloat16(w);
  float r = w - __bfloat162float(h);
  whi[i] = h;
  wlo[i] = __float2bfloat16(r);
}

// L0 packed weights: k = slot*8 + ci, 12 slots (9 taps + 3 zero), 8ch (3 real).
__global__ void wsplit_l0(const float* __restrict__ W0,
                          __hip_bfloat16* __restrict__ whi, __hip_bfloat16* __restrict__ wlo) {
  int i = blockIdx.x * 256 + threadIdx.x;      // co*96 + k
  if (i >= 64 * 96) return;
  int co = i / 96, k = i - co * 96;
  int slot = k >> 3, ci = k & 7;
  float w = 0.0f;
  if (slot < 9 && ci < 3) w = W0[((size_t)co * 3 + ci) * 9 + slot];
  __hip_bfloat16 h = __float2bfloat16(w);
  float r = w - __bfloat162float(h);
  whi[i] = h;
  wlo[i] = __float2bfloat16(r);
}

// Poisson generator for ALL timesteps -> [T][B*HW][8] (ch 3..7 zero), 16B store/px.
// Spikes depend only on (x,u): hoisted out of the timestep loop (1 dispatch).
__global__ void spike_gen8(const float* __restrict__ x, const float* __restrict__ u,
                           __hip_bfloat16* __restrict__ spk) {
  const int HW = 16384;
  int i = blockIdx.x * 256 + threadIdx.x;      // (t*BB+b)*HW + hw
  if (i >= TT * BB * HW) return;
  int hw = i & (HW - 1);
  int tb = i >> 14;                            // t*BB + b
  int b  = tb & 3;
  short8v o = {};
#pragma unroll
  for (int c = 0; c < 3; ++c) {
    float xv = x[((b * 3 + c) << 14) + hw];
    float uv = u[(((size_t)tb * 3 + c) << 14) + hw];
    float ax = fabsf(xv);
    float sg = (xv > 0.0f) ? 1.0f : ((xv < 0.0f) ? -1.0f : 0.0f);
    float s  = (uv <= ax) ? sg : 0.0f;
    __hip_bfloat16_raw raw = __hip_bfloat16_raw(__float2bfloat16(s));
    o[c] = (short)raw.x;
  }
  *(short8v*)(spk + (size_t)i * 8) = o;
}

// L0 dedicated (r13): tap-packed implicit GEMM, K = 96 (12 slots x 8ch), 3 chunks.
__global__ __launch_bounds__(256) void gemm_lif_l0(
    const __hip_bfloat16* __restrict__ spk,   // [B*HW][8] (this timestep's plane)
    const __hip_bfloat16* __restrict__ wsp,   // [2][64][96] hi, lo
    const float* __restrict__ bnt, float* __restrict__ mem,
    __hip_bfloat16* __restrict__ actout,
    const __hip_bfloat16* __restrict__ zp) {
  constexpr int M = 2, Co = 64, Kpk = 96, HW = 16384, H = 128, W = 128;
  __shared__ __hip_bfloat16 lds[3 * 64 * 32];     // 3 chunks x 64 rows x 32 (12 KB)
  const int lane = threadIdx.x & 63, wid = threadIdx.x >> 6;
  const int l15 = lane & 15, g = lane >> 4;

  const int nb = gridDim.x;                        // 1024
  const int flat = blockIdx.x;
  const int swz = (flat & 7) * (nb >> 3) + (flat >> 3);
  const int bx = swz & 511, by = swz >> 9;
  const int p0 = (bx * 4 + wid) * 32;
  const int co0 = by * 32;

  int b_[M], y_[M], x_[M];
#pragma unroll
  for (int m = 0; m < M; ++m) {
    int pb = p0 + m * 16;
    b_[m] = pb >> 14;
    int rem = pb & (HW - 1);
    y_[m] = rem >> 7;
    x_[m] = (rem & 127) + l15;
  }

  unsigned sgb[3];
#pragma unroll
  for (int i = 0; i < 3; ++i) {
    int f = wid * 48 + i * 16 + (lane >> 2);
    int cc = f >> 6;            // chunk
    int r  = f & 63;
    int half = r >> 5;          // 0 hi, 1 lo
    int co   = r & 31;
    int slot = (lane & 3) ^ ((co >> 1) & 3);
    sgb[i] = (unsigned)half * Co * Kpk + (unsigned)(co0 + co) * Kpk + slot * 8 + cc * 32;
  }
#pragma unroll
  for (int i = 0; i < 3; ++i) {
    const __hip_bfloat16* gp = wsp + sgb[i];
    __hip_bfloat16* lp = &lds[(wid * 48 + i * 16) * 32];
    __builtin_amdgcn_global_load_lds(
        (const __attribute__((address_space(1))) void*)gp,
        (__attribute__((address_space(3))) void*)lp, 16, 0, 0);
  }

  // A: 3 chunks x M frags; per-lane tap = chunk*4 + g
  short8v aA[3][M];
#pragma unroll
  for (int c = 0; c < 3; ++c) {
    int tap = c * 4 + g;
    int ty = (tap * 11) >> 5;
    int tx = tap - ty * 3;
    int dy = ty - 1, dx = tx - 1;
#pragma unroll
    for (int m = 0; m < M; ++m) {
      int sy = y_[m] + dy, sx = x_[m] + dx;
      bool v = (tap < 9) & (sy >= 0) & (sy < H) & (sx >= 0) & (sx < W);
      int pix = (b_[m] << 14) + (sy << 7) + sx;
      const __hip_bfloat16* ap = v ? (spk + (size_t)pix * 8) : zp;
      aA[c][m] = *(const short8v*)ap;
    }
  }

  asm volatile("s_waitcnt vmcnt(%0)" :: "n"(6) : "memory");  // 3 stage retired; 6 A in flight
  __builtin_amdgcn_s_barrier();
  __builtin_amdgcn_sched_barrier(0);

  f32x4 acc[M][2] = {};
  const int rdb = l15 * 32 + ((g ^ ((l15 >> 1) & 3)) * 8);
#pragma unroll
  for (int c = 0; c < 3; ++c) {
    short8v bh[2], bl[2];
#pragma unroll
    for (int j = 0; j < 2; ++j) {
      bh[j] = *(const short8v*)(&lds[c * 2048] + j * 512 + rdb);
      bl[j] = *(const short8v*)(&lds[c * 2048] + 1024 + j * 512 + rdb);
    }
    __builtin_amdgcn_s_setprio(1);
#pragma unroll
    for (int j = 0; j < 2; ++j)
#pragma unroll
      for (int m = 0; m < M; ++m) {
        acc[m][j] = __builtin_amdgcn_mfma_f32_16x16x32_bf16(aA[c][m], bh[j], acc[m][j], 0, 0, 0);
        acc[m][j] = __builtin_amdgcn_mfma_f32_16x16x32_bf16(aA[c][m], bl[j], acc[m][j], 0, 0, 0);
      }
    __builtin_amdgcn_s_setprio(0);
  }

  // epilogue: BN + LIF
#pragma unroll
  for (int j = 0; j < 2; ++j) {
    int c = co0 + j * 16 + l15;
    float ga = bnt[c], mu = bnt[Co + c], va = bnt[2 * Co + c];
    float sc = ga / sqrtf(va + BNEPS);
#pragma unroll
    for (int m = 0; m < M; ++m) {
      int pixb = p0 + m * 16 + 4 * g;
#pragma unroll
      for (int r = 0; r < 4; ++r) {
        size_t idx = (size_t)(pixb + r) * Co + c;
        float bno = (acc[m][j][r] - mu) * sc;
        float mv = LEAK * mem[idx] + bno;
        float s = (mv > THRS) ? 1.0f : 0.0f;
        actout[idx] = __float2bfloat16(s);
        mem[idx] = mv - s;
      }
    }
  }
}

// Generic implicit-GEMM conv3x3(pad==dil) + BN + LIF — r13 structure (best measured).
// Group pipeline: counted vmcnt at group top, per-chunk prefA/ds_read/MFMA
// interleave, setprio around MFMA cluster. SPLIT=2: in-block split-K, partials
// merged via LDS f32 planes (4B/lane stride -> conflict-free); epilogue on half 0.
template<int M, int N, int GRP, int CPT, int SPLIT>
__global__ __launch_bounds__(SPLIT * 256, 4) void gemm_lif(
    const __hip_bfloat16* __restrict__ actin,
    const __hip_bfloat16* __restrict__ wsp,      // [2][Co][Kpad] hi, lo
    const float* __restrict__ bnt,               // [3][Co] for this timestep
    float* __restrict__ mem, __hip_bfloat16* __restrict__ actout,
    const __hip_bfloat16* __restrict__ zp,       // zero page (>= Cip bf16, zeroed)
    int Co, int lgHW, int lgW, int dil, int lgGX) {
  constexpr int NW = 4;
  constexpr int Cip = CPT * 32;
  constexpr int Kpad = 9 * Cip;
  constexpr int lgcpt = (CPT == 1) ? 0 : (CPT == 2) ? 1 : (CPT == 4) ? 2 : 3;
  constexpr int R  = N * 32;
  constexpr int lgR = (N == 1) ? 5 : ((N == 2) ? 6 : 7);
  constexpr int BUFROWS = GRP * R;
  constexpr int BUFELEM = BUFROWS * 32;
  constexpr int INSTS = BUFROWS / (16 * NW);
  constexpr int AM = M * GRP;
  constexpr int WAITN = AM;
  constexpr int NCH = (9 * CPT) / SPLIT;
  constexpr int NGRP = NCH / GRP;
  static_assert(NCH % GRP == 0, "group must divide per-half chunk count");
  __shared__ __hip_bfloat16 lds[SPLIT * 2 * BUFELEM];

  const int HW = 1 << lgHW, H = HW >> lgW, W = 1 << lgW;
  const unsigned CoKpad = (unsigned)Co * Kpad;
  const int lane = threadIdx.x & 63, wid = threadIdx.x >> 6;
  const int kw = wid >> 2;
  const int wq = wid & 3;
  const int l15 = lane & 15, g = lane >> 4;
  __hip_bfloat16* ldsh = lds + kw * 2 * BUFELEM;

  const int nb = gridDim.x;
  const int flat = blockIdx.x;
  const int swz = (flat & 7) * (nb >> 3) + (flat >> 3);
  const int bx = swz & ((1 << lgGX) - 1);
  const int by = swz >> lgGX;
  const int p0  = (bx * NW + wq) * (M * 16);
  const int co0 = by * (N * 16);

  int b_[M], y_[M], x_[M];
#pragma unroll
  for (int m = 0; m < M; ++m) {
    int pb = p0 + m * 16;
    b_[m] = pb >> lgHW;
    int rem = pb & (HW - 1);
    y_[m] = rem >> lgW;
    x_[m] = (rem & (W - 1)) + l15;
  }

  const unsigned kbase = (unsigned)kw * (NCH * 32);
  unsigned sgb[INSTS];
#pragma unroll
  for (int i = 0; i < INSTS; ++i) {
    int f  = wq * (BUFROWS / NW) + i * 16 + (lane >> 2);
    int cc = f >> lgR;
    int r  = f & (R - 1);
    int half = r >> (lgR - 1);
    int co   = r & (16 * N - 1);
    int slot = (lane & 3) ^ ((co >> 1) & 3);
    sgb[i] = (unsigned)half * CoKpad + (unsigned)(co0 + co) * Kpad + slot * 8
           + cc * 32 + kbase;
  }

  auto stage = [&](int gl, int buf) {
#pragma unroll
    for (int i = 0; i < INSTS; ++i) {
      const __hip_bfloat16* gp = wsp + sgb[i] + gl * (GRP * 32);
      __hip_bfloat16* lp = &ldsh[buf * BUFELEM + (wq * (BUFROWS / NW) + i * 16) * 32];
      __builtin_amdgcn_global_load_lds(
          (const __attribute__((address_space(1))) void*)gp,
          (__attribute__((address_space(3))) void*)lp, 16, 0, 0);
    }
  };

  const __hip_bfloat16* apc[M];
  auto mkaddr = [&](int tap) {
    int ty = (tap * 11) >> 5;
    int tx = tap - ty * 3;
    int dy = (ty - 1) * dil, dx = (tx - 1) * dil;
#pragma unroll
    for (int m = 0; m < M; ++m) {
      int sy = y_[m] + dy, sx = x_[m] + dx;
      bool v = (sy >= 0) & (sy < H) & (sx >= 0) & (sx < W);
      int pix = (b_[m] << lgHW) + (sy << lgW) + sx;
      apc[m] = v ? (actin + (size_t)pix * Cip + 8 * g) : (zp + 8 * g);
    }
  };

  auto prefA_slice = [&](int cg, int cc, short8v (&dst)[GRP][M], bool force) {
    if ((cg & (CPT - 1)) == 0 || force) mkaddr(cg >> lgcpt);
    int kc = (cg & (CPT - 1)) << 5;
#pragma unroll
    for (int m = 0; m < M; ++m)
      dst[cc][m] = *(const short8v*)(apc[m] + kc);
  };

  f32x4 acc[M][N] = {};
  const int rdb = l15 * 32 + ((g ^ ((l15 >> 1) & 3)) * 8);

  short8v aA[GRP][M], aB[GRP][M];

  auto grp_body = [&](int gi, short8v (&aU)[GRP][M], short8v (&aF)[GRP][M]) {
    asm volatile("s_waitcnt vmcnt(%0)" :: "n"(WAITN) : "memory");
    __builtin_amdgcn_s_barrier();
    __builtin_amdgcn_sched_barrier(0);

    const bool more = (gi + 1 < NGRP);
    if (more) stage(gi + 1, (gi + 1) & 1);

    const __hip_bfloat16* bp = &ldsh[(gi & 1) * BUFELEM];
#pragma unroll
    for (int cc = 0; cc < GRP; ++cc) {
      if (more) prefA_slice(kw * NCH + (gi + 1) * GRP + cc, cc, aF, false);
      short8v bh[N], bl[N];
#pragma unroll
      for (int j = 0; j < N; ++j) {
        bh[j] = *(const short8v*)(bp + cc * (R * 32) + j * 512 + rdb);
        bl[j] = *(const short8v*)(bp + cc * (R * 32) + (N * 512) + j * 512 + rdb);
      }
      __builtin_amdgcn_s_setprio(1);
#pragma unroll
      for (int j = 0; j < N; ++j)
#pragma unroll
        for (int m = 0; m < M; ++m) {
          acc[m][j] = __builtin_amdgcn_mfma_f32_16x16x32_bf16(aU[cc][m], bh[j], acc[m][j], 0, 0, 0);
          acc[m][j] = __builtin_amdgcn_mfma_f32_16x16x32_bf16(aU[cc][m], bl[j], acc[m][j], 0, 0, 0);
        }
      __builtin_amdgcn_s_setprio(0);
    }
  };

  stage(0, 0);
#pragma unroll
  for (int cc = 0; cc < GRP; ++cc)
    prefA_slice(kw * NCH + cc, cc, aA, cc == 0);

#pragma unroll
  for (int gi = 0; gi < NGRP; ++gi) {
    if (gi & 1) grp_body(gi, aB, aA);
    else        grp_body(gi, aA, aB);
  }

  if constexpr (SPLIT == 2) {
    asm volatile("s_waitcnt vmcnt(0) lgkmcnt(0)" ::: "memory");
    __builtin_amdgcn_s_barrier();
    float* red = (float*)lds;
    const int tid = wq * 64 + lane;
    if (kw == 1) {
#pragma unroll
      for (int m = 0; m < M; ++m)
#pragma unroll
        for (int j = 0; j < N; ++j)
#pragma unroll
          for (int r = 0; r < 4; ++r)
            red[((m * N + j) * 4 + r) * 256 + tid] = acc[m][j][r];
    }
    asm volatile("s_waitcnt lgkmcnt(0)" ::: "memory");
    __builtin_amdgcn_s_barrier();
    if (kw == 1) return;
#pragma unroll
    for (int m = 0; m < M; ++m)
#pragma unroll
      for (int j = 0; j < N; ++j)
#pragma unroll
        for (int r = 0; r < 4; ++r)
          acc[m][j][r] += red[((m * N + j) * 4 + r) * 256 + tid];
  }

#pragma unroll
  for (int j = 0; j < N; ++j) {
    int c = co0 + j * 16 + l15;
    float ga = bnt[c], mu = bnt[Co + c], va = bnt[2 * Co + c];
    float sc = ga / sqrtf(va + BNEPS);
#pragma unroll
    for (int m = 0; m < M; ++m) {
      int pixb = p0 + m * 16 + 4 * g;
#pragma unroll
      for (int r = 0; r < 4; ++r) {
        size_t idx = (size_t)(pixb + r) * Co + c;
        float bno = (acc[m][j][r] - mu) * sc;
        float mv = LEAK * mem[idx] + bno;
        float s = (mv > THRS) ? 1.0f : 0.0f;
        actout[idx] = __float2bfloat16(s);
        mem[idx] = mv - s;
      }
    }
  }
}

// AvgPool(3,2,1) storing SUM (exact ints in bf16); /9 folded into next layer weights.
__global__ void avgpool_sum8(const __hip_bfloat16* __restrict__ in,
                             __hip_bfloat16* __restrict__ out, int C, int H, int W) {
  const int Ho = H >> 1, Wo = W >> 1;
  const int C8 = C >> 3;
  const int n = BB * Ho * Wo * C8;
  int i = blockIdx.x * 256 + threadIdx.x;
  if (i >= n) return;
  int c8 = i % C8; int t = i / C8;
  int xo = t % Wo; t /= Wo;
  int yo = t % Ho; int b = t / Ho;
  const int y0 = 2 * yo - 1, x0 = 2 * xo - 1;
  float s[8] = {0, 0, 0, 0, 0, 0, 0, 0};
#pragma unroll
  for (int dy = 0; dy < 3; ++dy) {
    int iy = y0 + dy;
    if (iy < 0 || iy >= H) continue;
#pragma unroll
    for (int dx = 0; dx < 3; ++dx) {
      int ix = x0 + dx;
      if (ix < 0 || ix >= W) continue;
      short8v v = *(const short8v*)(in + (((size_t)b * H + iy) * W + ix) * C + c8 * 8);
#pragma unroll
      for (int e = 0; e < 8; ++e) {
        __hip_bfloat16_raw raw; raw.x = (unsigned short)v[e];
        s[e] += __bfloat162float(__hip_bfloat16(raw));
      }
    }
  }
  short8v o;
#pragma unroll
  for (int e = 0; e < 8; ++e) {
    __hip_bfloat16_raw raw = __hip_bfloat16_raw(__float2bfloat16(s[e]));
    o[e] = (short)raw.x;
  }
  *(short8v*)(out + (size_t)i * 8) = o;
}

// 1x1 conv 1024->21 @32x32, f32, accumulate into d_out. One wave per (b,pix).
__global__ void out_conv(const __hip_bfloat16* __restrict__ act,  // [B*1024px][1024ch]
                         const float* __restrict__ W8, float* __restrict__ out) {
  int gw = (blockIdx.x * 256 + threadIdx.x) >> 6;  // b*1024 + pix
  int lane = threadIdx.x & 63;
  int b = gw >> 10, pix = gw & 1023;
  const __hip_bfloat16* ap = act + ((size_t)gw << 10);
  float acc[NCLS];
#pragma unroll
  for (int c = 0; c < NCLS; ++c) acc[c] = 0.0f;
  for (int j = 0; j < 16; ++j) {
    int ci = j * 64 + lane;
    float av = __bfloat162float(ap[ci]);
#pragma unroll
    for (int c = 0; c < NCLS; ++c) acc[c] = fmaf(av, W8[c * 1024 + ci], acc[c]);
  }
#pragma unroll
  for (int c = 0; c < NCLS; ++c) {
    float v = acc[c];
    for (int off = 32; off; off >>= 1) v += __shfl_xor(v, off, 64);
    if (lane == 0) out[((size_t)b * NCLS + c) * 1024 + pix] += v;
  }
}

extern "C" void kernel_launch(void* const* d_in, const int* in_sizes, int n_in,
                              void* d_out, int out_size, void* d_ws, size_t ws_size,
                              hipStream_t stream) {
  const float* x = (const float*)d_in[0];
  const float* u = (const float*)d_in[1];
  const float* Wc[9];
  for (int i = 0; i < 9; ++i) Wc[i] = (const float*)d_in[2 + i];
  const float* bn[8];
  for (int i = 0; i < 8; ++i) bn[i] = (const float*)d_in[11 + i];

  const int Ci_[8]  = {3, 64, 64, 128, 128, 256, 256, 256};
  const int Cip_[8] = {8, 64, 64, 128, 128, 256, 256, 256};
  const int Co_[8]  = {64, 64, 128, 128, 256, 256, 256, 1024};
  const int HH_[8]  = {128, 128, 64, 64, 32, 32, 32, 32};
  const float wsc_[8] = {1.f, 1.f, 1.f / 9.f, 1.f, 1.f / 9.f, 1.f, 1.f, 1.f};

  float* ws = (float*)d_ws;
  size_t off = 0;
  auto align8 = [](size_t v) { return (v + 7) & ~(size_t)7; };

  float* memp[8];
  for (int i = 0; i < 8; ++i) {
    memp[i] = ws + off;
    off += (size_t)BB * HH_[i] * HH_[i] * Co_[i];
  }
  __hip_bfloat16* zp = (__hip_bfloat16*)(ws + off);   // zero page (1 KB)
  off += 256;
  const size_t zero_floats = off;                     // mem + zp zeroed each call
  __hip_bfloat16* spk = (__hip_bfloat16*)(ws + off);  // [T][B*HW][8], fully rewritten
  off += (size_t)TT * BB * 16384 * 8 / 2;
  __hip_bfloat16* actA = (__hip_bfloat16*)(ws + off); off += 2097152;
  __hip_bfloat16* actB = (__hip_bfloat16*)(ws + off); off += 2097152;
  __hip_bfloat16* wall[8];
  wall[0] = (__hip_bfloat16*)(ws + off);
  off = align8(off + (size_t)64 * 96);
  for (int i = 1; i < 8; ++i) {
    size_t n = (size_t)Co_[i] * 9 * Cip_[i];
    wall[i] = (__hip_bfloat16*)(ws + off);
    off = align8(off + n);
  }

  zero_f32<<<2048, 256, 0, stream>>>(ws, (int)zero_floats);
  zero_f32<<<(BB * NCLS * 1024 + 255) / 256, 256, 0, stream>>>((float*)d_out, BB * NCLS * 1024);

  wsplit_l0<<<(64 * 96 + 255) / 256, 256, 0, stream>>>(Wc[0], wall[0], wall[0] + 64 * 96);
  for (int i = 1; i < 8; ++i) {
    int n = Co_[i] * 9 * Cip_[i];
    wsplit<<<(n + 255) / 256, 256, 0, stream>>>(Wc[i], wall[i], wall[i] + n,
                                                Co_[i], Ci_[i], Cip_[i], wsc_[i]);
  }

  // all timesteps' spikes in one dispatch (depends only on x,u)
  spike_gen8<<<(TT * BB * 16384 + 255) / 256, 256, 0, stream>>>(x, u, spk);

  const size_t spkT = (size_t)BB * 16384 * 8;
  for (int t = 0; t < TT; ++t) {
    // L0: tap-packed, grid 1024 (4 waves/SIMD), K=96
    gemm_lif_l0<<<1024, 256, 0, stream>>>(spk + (size_t)t * spkT, wall[0],
                                          bn[0] + (size_t)t * 3 * 64, memp[0], actA, zp);
    // L1: 64->64 @128      wave 32x32, grid 1024
    gemm_lif<2, 2, 3, 2, 1><<<1024, 256, 0, stream>>>(actA, wall[1], bn[1] + (size_t)t * 3 * 64,   memp[1], actB, zp, 64,   14, 7, 1, 9);
    avgpool_sum8<<<(BB * 64 * 64 * 8 + 255) / 256, 256, 0, stream>>>(actB, actA, 64, 128, 128);
    // L2: 64->128 @64 (w/9)  wave 32x32, split-K x2, 512 blk x 512 thr
    gemm_lif<2, 2, 3, 2, 2><<<512, 512, 0, stream>>>(actA, wall[2], bn[2] + (size_t)t * 3 * 128,  memp[2], actB, zp, 128,  12, 6, 1, 7);
    // L3: 128->128 @64       split-K x2
    gemm_lif<2, 2, 3, 4, 2><<<512, 512, 0, stream>>>(actB, wall[3], bn[3] + (size_t)t * 3 * 128,  memp[3], actA, zp, 128,  12, 6, 1, 7);
    avgpool_sum8<<<(BB * 32 * 32 * 16 + 255) / 256, 256, 0, stream>>>(actA, actB, 128, 64, 64);
    // L4: 128->256 @32 (w/9) wave 16x32, split-K x2
    gemm_lif<1, 2, 3, 4, 2><<<512, 512, 0, stream>>>(actB, wall[4], bn[4] + (size_t)t * 3 * 256,   memp[4], actA, zp, 256,  10, 5, 1, 6);
    // L5: 256->256 @32 dil2  split-K x2
    gemm_lif<1, 2, 4, 8, 2><<<512, 512, 0, stream>>>(actA, wall[5], bn[5] + (size_t)t * 3 * 256,   memp[5], actB, zp, 256,  10, 5, 2, 6);
    // L6: 256->256 @32 dil2  split-K x2
    gemm_lif<1, 2, 4, 8, 2><<<512, 512, 0, stream>>>(actB, wall[6], bn[6] + (size_t)t * 3 * 256,   memp[6], actA, zp, 256,  10, 5, 2, 6);
    // L7: 256->1024 @32 dil12  wave 32x64, split-K x2
    gemm_lif<2, 4, 2, 8, 2><<<512, 512, 0, stream>>>(actA, wall[7], bn[7] + (size_t)t * 3 * 1024, memp[7], actB, zp, 1024, 10, 5, 12, 5);
    // output layer accumulation
    out_conv<<<dim3(BB * 1024 / 4), 256, 0, stream>>>(actB, Wc[8], (float*)d_out);
  }
  scale_f32<<<(BB * NCLS * 1024 + 255) / 256, 256, 0, stream>>>((float*)d_out, BB * NCLS * 1024, 1.0f / TT);
}